// Round 6
// baseline (86551.440 us; speedup 1.0000x reference)
//
#include <hip/hip_runtime.h>
#include <math.h>

// mLSTM scan, 8192 serial steps. Weights resident on-chip (wh_w f32 in
// regs: 256/thread; wmh_w bf16-packed in LDS: 32KB/CU), one persistent
// workgroup per CU (256 x 256), per-step cross-CU exchange of the
// 2048-vectors m and h through the LLC. Final FC chain on block 0 only.
//
// R5 -> R6: producer stores become no-return global_atomic_swap_x2
// (__hip_atomic_exchange, relaxed, agent scope). Rationale: sc1 plain
// stores write through toward HBM WITHOUT allocating in the LLC (evidence:
// FETCH_SIZE 3 GB for a 48KB working set), so every fresh exchange line
// cost an HBM round-trip on first consumer read -- the ~3us/phase constant
// that survived R4/R5 protocol surgery. Atomics execute AT the memory-side
// LLC: the line is updated/allocated there, and consumer sc1 poll loads
// hit the LLC. Packet format, poll loops, and protocol are unchanged.

#define WS_HP   0          // h pairs: 2048 x (val,tag) = 4096 words
#define WS_MP   4096       // m pairs: 4096 words
#define WS_CP   8192       // c pairs: 4096 words
#define WS_TOT  12288      // words

typedef unsigned u32x4 __attribute__((ext_vector_type(4)));
typedef unsigned u32x2 __attribute__((ext_vector_type(2)));

__device__ __forceinline__ float sigm(float x) { return 1.f / (1.f + __expf(-x)); }

__device__ __forceinline__ float wred(float v) {
  v += __shfl_xor(v, 32, 64);
  v += __shfl_xor(v, 16, 64);
  v += __shfl_xor(v, 8, 64);
  v += __shfl_xor(v, 4, 64);
  v += __shfl_xor(v, 2, 64);
  v += __shfl_xor(v, 1, 64);
  return v;
}

// Publish one (value, tag) pair as an 8B atomic exchange executed AT the
// LLC (no-return form; line allocated/updated in LLC, no HBM round-trip).
__device__ __forceinline__ void store_pair(unsigned* p, float v, unsigned tag) {
  unsigned long long q = (unsigned long long)__float_as_uint(v)
                       | ((unsigned long long)tag << 32);
  __hip_atomic_exchange((unsigned long long*)p, q,
                        __ATOMIC_RELAXED, __HIP_MEMORY_SCOPE_AGENT);
}

// Load 8 pairs (64B) from LLC; returns true when all 8 tags == expect.
__device__ __forceinline__ bool poll8(const unsigned* p, unsigned expect,
                                      float4* v0, float4* v1) {
  u32x4 a, b, c, d;
  asm volatile(
      "global_load_dwordx4 %0, %4, off sc0 sc1\n\t"
      "global_load_dwordx4 %1, %4, off offset:16 sc0 sc1\n\t"
      "global_load_dwordx4 %2, %4, off offset:32 sc0 sc1\n\t"
      "global_load_dwordx4 %3, %4, off offset:48 sc0 sc1\n\t"
      "s_waitcnt vmcnt(0)"
      : "=&v"(a), "=&v"(b), "=&v"(c), "=&v"(d)
      : "v"(p)
      : "memory");
  bool ok = (a.y == expect) & (a.w == expect) & (b.y == expect) & (b.w == expect)
          & (c.y == expect) & (c.w == expect) & (d.y == expect) & (d.w == expect);
  v0->x = __uint_as_float(a.x); v0->y = __uint_as_float(a.z);
  v0->z = __uint_as_float(b.x); v0->w = __uint_as_float(b.z);
  v1->x = __uint_as_float(c.x); v1->y = __uint_as_float(c.z);
  v1->z = __uint_as_float(d.x); v1->w = __uint_as_float(d.z);
  return ok;
}

// Scalar pair poll (FC tail only).
__device__ __forceinline__ float poll1(const unsigned* p, unsigned expect) {
  for (;;) {
    u32x2 q;
    asm volatile("global_load_dwordx2 %0, %1, off sc0 sc1\n\t"
                 "s_waitcnt vmcnt(0)"
                 : "=&v"(q) : "v"(p) : "memory");
    if (q.y == expect) return __uint_as_float(q.x);
    __builtin_amdgcn_s_sleep(1);
  }
}

__global__ __launch_bounds__(256, 1)
void mlstm_kernel(const int* __restrict__ tokens,
                  const float* __restrict__ embed_w,
                  const float* __restrict__ wx_w,  const float* __restrict__ wx_b,
                  const float* __restrict__ wh_w,  const float* __restrict__ wh_b,
                  const float* __restrict__ wmx_w, const float* __restrict__ wmx_b,
                  const float* __restrict__ wmh_w, const float* __restrict__ wmh_b,
                  const float* __restrict__ fc1_w, const float* __restrict__ fc1_b,
                  const float* __restrict__ fc2_w, const float* __restrict__ fc2_b,
                  const float* __restrict__ fc3_w, const float* __restrict__ fc3_b,
                  const float* __restrict__ fc4_w, const float* __restrict__ fc4_b,
                  float* __restrict__ out, float* __restrict__ ws)
{
  __shared__ unsigned wmh_pk[8][16][64];          // 32KB: wmh rows, bf16x2 packed
  __shared__ float gate_lds[4][8];
  __shared__ __align__(16) float fcx[4096];       // gather stage (loop) / FC scratch
  __shared__ __align__(16) float fy[2048];

  const int tid  = threadIdx.x;
  const int lane = tid & 63;
  const int wv   = tid >> 6;        // wave 0..3 == gate type i,f,g,o
  const int b    = blockIdx.x;      // CU id 0..255

  unsigned* h_pairs = (unsigned*)ws + WS_HP;
  unsigned* m_pairs = (unsigned*)ws + WS_MP;
  unsigned* c_pairs = (unsigned*)ws + WS_CP;
  float* stage = fcx;               // 2048-float gather buffer (aliased)

  // ---------------- preload weights ----------------
  float whR[8][32];
  float wxR[8][2];
  float gBias[8];
  {
    const int gr0 = 2048 * wv + 8 * b;
#pragma unroll
    for (int s = 0; s < 8; ++s) {
      const float* row = wh_w + (size_t)(gr0 + s) * 2048;
#pragma unroll
      for (int j = 0; j < 32; ++j) whR[s][j] = row[lane + 64 * j];
      wxR[s][0] = wx_w[(size_t)(gr0 + s) * 128 + lane];
      wxR[s][1] = wx_w[(size_t)(gr0 + s) * 128 + lane + 64];
      gBias[s] = wh_b[gr0 + s] + wx_b[gr0 + s];
    }
  }
  float wmxR[2][2], vB[2], xB[2];
#pragma unroll
  for (int rr = 0; rr < 2; ++rr) {
    const int gu = 8 * b + 2 * wv + rr;
    wmxR[rr][0] = wmx_w[(size_t)gu * 128 + lane];
    wmxR[rr][1] = wmx_w[(size_t)gu * 128 + lane + 64];
    vB[rr] = wmh_b[gu];
    xB[rr] = wmx_b[gu];
  }
  // wmh rows -> LDS as packed bf16 pairs (RNE).
  for (int idx = tid; idx < 8 * 16 * 64; idx += 256) {
    int u = idx >> 10, p = (idx >> 6) & 15, l = idx & 63;
    float a = wmh_w[(size_t)(8 * b + u) * 2048 + l + 128 * p];
    float c = wmh_w[(size_t)(8 * b + u) * 2048 + l + 128 * p + 64];
    unsigned xa = __float_as_uint(a); xa = (xa + 0x7fffu + ((xa >> 16) & 1u)) >> 16;
    unsigned xc = __float_as_uint(c); xc = (xc + 0x7fffu + ((xc >> 16) & 1u)) >> 16;
    wmh_pk[u][p][l] = xa | (xc << 16);
  }
  __syncthreads();

  float creg = 0.f;
  int tok = tokens[0];
  float e0 = embed_w[tok * 128 + lane];
  float e1 = embed_w[tok * 128 + lane + 64];

  for (int t = 0; t < 8192; ++t) {
    // ---- phase 1: poll h(t) pairs (tag == t; t=0 served by memset zeros) ----
    {
      float4 v0, v1;
      while (!poll8(h_pairs + 16 * tid, (unsigned)t, &v0, &v1))
        __builtin_amdgcn_s_sleep(1);
      *(float4*)&stage[tid * 8]     = v0;
      *(float4*)&stage[tid * 8 + 4] = v1;
    }
    __syncthreads();                      // stage complete
    float hloc[32];
#pragma unroll
    for (int j = 0; j < 32; ++j) hloc[j] = stage[lane + 64 * j];
#pragma unroll
    for (int rr = 0; rr < 2; ++rr) {
      const int u = 2 * wv + rr;
      float acc = 0.f;
#pragma unroll
      for (int p = 0; p < 16; ++p) {
        unsigned pk = wmh_pk[u][p][lane];
        acc = fmaf(__uint_as_float(pk << 16),         hloc[2 * p],     acc);
        acc = fmaf(__uint_as_float(pk & 0xffff0000u), hloc[2 * p + 1], acc);
      }
      float ax = fmaf(wmxR[rr][0], e0, wmxR[rr][1] * e1);
      acc = wred(acc);
      ax  = wred(ax);
      if (lane == 0) {
        float m = (ax + xB[rr]) * (acc + vB[rr]);   // m = xm * (wmh@h + b)
        store_pair(m_pairs + 2 * (8 * b + u), m, (unsigned)(t + 1));
      }
    }
    __syncthreads();   // all stage reads done before phase-2 poll overwrites

    // ---- phase 2: poll m(t) pairs (tag == t+1) ----
    {
      float4 v0, v1;
      while (!poll8(m_pairs + 16 * tid, (unsigned)(t + 1), &v0, &v1))
        __builtin_amdgcn_s_sleep(1);
      *(float4*)&stage[tid * 8]     = v0;
      *(float4*)&stage[tid * 8 + 4] = v1;
    }
    __syncthreads();
    float mloc[32];
#pragma unroll
    for (int j = 0; j < 32; ++j) mloc[j] = stage[lane + 64 * j];
    float ga[8];
#pragma unroll
    for (int s = 0; s < 8; ++s) {
      float acc = fmaf(wxR[s][0], e0, wxR[s][1] * e1);   // x_gates folded in
#pragma unroll
      for (int j = 0; j < 32; ++j) acc = fmaf(whR[s][j], mloc[j], acc);
      ga[s] = acc;
    }
    // prefetch next token + embedding (hides under reduce/exchange)
    if (t + 1 < 8192) {
      tok = tokens[t + 1];
      e0 = embed_w[tok * 128 + lane];
      e1 = embed_w[tok * 128 + lane + 64];
    }
#pragma unroll
    for (int s = 0; s < 8; ++s) {
      float r = wred(ga[s]);
      if (lane == 0) gate_lds[wv][s] = r + gBias[s];
    }
    __syncthreads();   // gate_lds complete; stage dead -> next poll may overwrite
    if (tid < 8) {
      float gi = gate_lds[0][tid], gf = gate_lds[1][tid];
      float gg = gate_lds[2][tid], go = gate_lds[3][tid];
      float c = sigm(gf) * creg + sigm(gi) * tanhf(gg);
      creg = c;
      float h = sigm(go) * tanhf(c);
      store_pair(h_pairs + 2 * (8 * b + tid), h, (unsigned)(t + 1));
    }
  }

  // ---- publish c (tag 8193 distinguishes from memset 0) ----
  if (tid < 8)
    store_pair(c_pairs + 2 * (8 * b + tid), creg, 8193u);

  if (b != 0) return;

  // ---- final FC chain on block 0 only (~10 MMAC) ----
  // h(8192) pairs carry tag 8192; c pairs tag 8193.
  for (int i = tid; i < 2048; i += 256) {
    fcx[i]        = poll1(h_pairs + 2 * i, 8192u);
    fcx[2048 + i] = poll1(c_pairs + 2 * i, 8193u);
  }
  __syncthreads();
  // fc1: [2048 x 4096]
  for (int r = tid; r < 2048; r += 256) {
    const float4* wr = (const float4*)(fc1_w + (size_t)r * 4096);
    const float4* xv = (const float4*)fcx;
    float a0 = 0, a1 = 0, a2 = 0, a3 = 0;
    for (int k = 0; k < 1024; ++k) {
      float4 w = wr[k], x = xv[k];
      a0 = fmaf(w.x, x.x, a0); a1 = fmaf(w.y, x.y, a1);
      a2 = fmaf(w.z, x.z, a2); a3 = fmaf(w.w, x.w, a3);
    }
    fy[r] = fmaxf((a0 + a1) + (a2 + a3) + fc1_b[r], 0.f);
  }
  __syncthreads();
  // fc2: [512 x 2048]
  for (int r = tid; r < 512; r += 256) {
    const float4* wr = (const float4*)(fc2_w + (size_t)r * 2048);
    const float4* xv = (const float4*)fy;
    float a0 = 0, a1 = 0, a2 = 0, a3 = 0;
    for (int k = 0; k < 512; ++k) {
      float4 w = wr[k], x = xv[k];
      a0 = fmaf(w.x, x.x, a0); a1 = fmaf(w.y, x.y, a1);
      a2 = fmaf(w.z, x.z, a2); a3 = fmaf(w.w, x.w, a3);
    }
    fcx[r] = fmaxf((a0 + a1) + (a2 + a3) + fc2_b[r], 0.f);
  }
  __syncthreads();
  // fc3: [1024 x 512]
  for (int r = tid; r < 1024; r += 256) {
    const float4* wr = (const float4*)(fc3_w + (size_t)r * 512);
    const float4* xv = (const float4*)fcx;
    float a0 = 0, a1 = 0, a2 = 0, a3 = 0;
    for (int k = 0; k < 128; ++k) {
      float4 w = wr[k], x = xv[k];
      a0 = fmaf(w.x, x.x, a0); a1 = fmaf(w.y, x.y, a1);
      a2 = fmaf(w.z, x.z, a2); a3 = fmaf(w.w, x.w, a3);
    }
    fy[r] = fmaxf((a0 + a1) + (a2 + a3) + fc3_b[r], 0.f);
  }
  __syncthreads();
  // fc4: [5 x 1024]
  if (tid < 5) {
    const float4* wr = (const float4*)(fc4_w + (size_t)tid * 1024);
    const float4* xv = (const float4*)fy;
    float a0 = 0, a1 = 0, a2 = 0, a3 = 0;
    for (int k = 0; k < 256; ++k) {
      float4 w = wr[k], x = xv[k];
      a0 = fmaf(w.x, x.x, a0); a1 = fmaf(w.y, x.y, a1);
      a2 = fmaf(w.z, x.z, a2); a3 = fmaf(w.w, x.w, a3);
    }
    out[tid] = fmaxf((a0 + a1) + (a2 + a3) + fc4_b[tid], 0.f);
  }
}

extern "C" void kernel_launch(void* const* d_in, const int* in_sizes, int n_in,
                              void* d_out, int out_size, void* d_ws, size_t ws_size,
                              hipStream_t stream)
{
  const int*   tokens = (const int*)  d_in[0];
  const float* embed_w = (const float*)d_in[1];
  const float* wx_w   = (const float*)d_in[2];
  const float* wx_b   = (const float*)d_in[3];
  const float* wh_w   = (const float*)d_in[4];
  const float* wh_b   = (const float*)d_in[5];
  const float* wmx_w  = (const float*)d_in[6];
  const float* wmx_b  = (const float*)d_in[7];
  const float* wmh_w  = (const float*)d_in[8];
  const float* wmh_b  = (const float*)d_in[9];
  const float* fc1_w  = (const float*)d_in[10];
  const float* fc1_b  = (const float*)d_in[11];
  const float* fc2_w  = (const float*)d_in[12];
  const float* fc2_b  = (const float*)d_in[13];
  const float* fc3_w  = (const float*)d_in[14];
  const float* fc3_b  = (const float*)d_in[15];
  const float* fc4_w  = (const float*)d_in[16];
  const float* fc4_b  = (const float*)d_in[17];
  float* out = (float*)d_out;
  float* ws  = (float*)d_ws;

  // zero all pair tags every call (graph-replay safe; h tags 0 == h(0)=0)
  hipMemsetAsync(d_ws, 0, WS_TOT * sizeof(float), stream);

  mlstm_kernel<<<dim3(256), dim3(256), 0, stream>>>(
      tokens, embed_w, wx_w, wx_b, wh_w, wh_b,
      wmx_w, wmx_b, wmh_w, wmh_b,
      fc1_w, fc1_b, fc2_w, fc2_b, fc3_w, fc3_b,
      fc4_w, fc4_b, out, ws);
}

// Round 7
// 74341.553 us; speedup vs baseline: 1.1642x; 1.1642x over previous
//
#include <hip/hip_runtime.h>
#include <math.h>

// mLSTM scan, 8192 serial steps. Weights resident on-chip (wh_w f32 in
// regs: 256/thread; wmh_w bf16-packed in LDS: 32KB/CU), one persistent
// workgroup per CU (256 x 256), per-step cross-CU exchange of the
// 2048-vectors m and h through the coherent point. FC chain on block 0.
//
// R6 -> R7:
//  1. Exchange packets: 2 x bf16 values + tag32 in ONE atomic 8B store
//     (4 B/scalar). Halves distinct exchange lines per phase (128 -> 64)
//     and halves poll loads (2x dwordx4 per consumer thread). Theory:
//     per-phase cost is dominated by per-LINE cross-XCD coherence
//     (probe/invalidate + refetch), so line count is the lever.
//  2. Wave remap: wave wv owns units {2wv, 2wv+1} for m AND all 4 gate
//     rows; butterfly wred leaves all 8 gate sums in every lane ->
//     c/h update in-wave. gate_lds + 1 barrier + tid<8 section deleted.
//  3. Dual LDS stage buffers (stageH=fcx, stageM=fy): 2 barriers/step.
//     Race-freedom: stageH writes (t+1) happen after SYNC_B(t) which is
//     after all hloc reads (t); stageM writes (t+1) after SYNC_A(t+1)
//     which is after all mloc reads (t).
//  c-state stays f32 locally; final h/c published as f32 (val,tag) pairs.

#define WS_HP   0          // h packets: 1024 x (bf16x2, tag) = 2048 words
#define WS_MP   2048       // m packets: 2048 words
#define WS_HF   4096       // final h: 2048 x (f32, tag) = 4096 words
#define WS_CF   8192       // final c: 4096 words
#define WS_TOT  12288      // words (48 KB)

typedef unsigned u32x4 __attribute__((ext_vector_type(4)));
typedef unsigned u32x2 __attribute__((ext_vector_type(2)));

__device__ __forceinline__ float sigm(float x) { return 1.f / (1.f + __expf(-x)); }

__device__ __forceinline__ float wred(float v) {
  v += __shfl_xor(v, 32, 64);
  v += __shfl_xor(v, 16, 64);
  v += __shfl_xor(v, 8, 64);
  v += __shfl_xor(v, 4, 64);
  v += __shfl_xor(v, 2, 64);
  v += __shfl_xor(v, 1, 64);
  return v;
}

// RNE f32 -> bf16 bits (low 16).
__device__ __forceinline__ unsigned bf(float f) {
  unsigned x = __float_as_uint(f);
  return (x + 0x7fffu + ((x >> 16) & 1u)) >> 16;
}

// One 8B packet: (bf16 v0 | bf16 v1 << 16, tag32), single atomic store.
__device__ __forceinline__ void store_pack(unsigned* p, float v0, float v1,
                                           unsigned tag) {
  u32x2 q; q.x = bf(v0) | (bf(v1) << 16); q.y = tag;
  asm volatile("global_store_dwordx2 %0, %1, off sc0 sc1"
               :: "v"(p), "v"(q) : "memory");
}

// f32 (value, tag) pair store (finals only).
__device__ __forceinline__ void store_pair(unsigned* p, float v, unsigned tag) {
  u32x2 q; q.x = __float_as_uint(v); q.y = tag;
  asm volatile("global_store_dwordx2 %0, %1, off sc0 sc1"
               :: "v"(p), "v"(q) : "memory");
}

// Poll 4 packets (32B = 8 scalars); true when all 4 tags == expect.
__device__ __forceinline__ bool poll4p(const unsigned* p, unsigned expect,
                                       u32x4* va, u32x4* vb) {
  u32x4 a, b;
  asm volatile(
      "global_load_dwordx4 %0, %2, off sc0 sc1\n\t"
      "global_load_dwordx4 %1, %2, off offset:16 sc0 sc1\n\t"
      "s_waitcnt vmcnt(0)"
      : "=&v"(a), "=&v"(b) : "v"(p) : "memory");
  bool ok = (a.y == expect) & (a.w == expect) & (b.y == expect) & (b.w == expect);
  *va = a; *vb = b;
  return ok;
}

// Scalar f32 pair poll (FC tail only).
__device__ __forceinline__ float poll1(const unsigned* p, unsigned expect) {
  for (;;) {
    u32x2 q;
    asm volatile("global_load_dwordx2 %0, %1, off sc0 sc1\n\t"
                 "s_waitcnt vmcnt(0)"
                 : "=&v"(q) : "v"(p) : "memory");
    if (q.y == expect) return __uint_as_float(q.x);
    __builtin_amdgcn_s_sleep(1);
  }
}

// Unpack 8 bf16 scalars from 2 packets' value-dwords into LDS stage.
__device__ __forceinline__ void stage8(float* s, u32x4 a, u32x4 b) {
  s[0] = __uint_as_float(a.x << 16);
  s[1] = __uint_as_float(a.x & 0xffff0000u);
  s[2] = __uint_as_float(a.z << 16);
  s[3] = __uint_as_float(a.z & 0xffff0000u);
  s[4] = __uint_as_float(b.x << 16);
  s[5] = __uint_as_float(b.x & 0xffff0000u);
  s[6] = __uint_as_float(b.z << 16);
  s[7] = __uint_as_float(b.z & 0xffff0000u);
}

__global__ __launch_bounds__(256, 1)
void mlstm_kernel(const int* __restrict__ tokens,
                  const float* __restrict__ embed_w,
                  const float* __restrict__ wx_w,  const float* __restrict__ wx_b,
                  const float* __restrict__ wh_w,  const float* __restrict__ wh_b,
                  const float* __restrict__ wmx_w, const float* __restrict__ wmx_b,
                  const float* __restrict__ wmh_w, const float* __restrict__ wmh_b,
                  const float* __restrict__ fc1_w, const float* __restrict__ fc1_b,
                  const float* __restrict__ fc2_w, const float* __restrict__ fc2_b,
                  const float* __restrict__ fc3_w, const float* __restrict__ fc3_b,
                  const float* __restrict__ fc4_w, const float* __restrict__ fc4_b,
                  float* __restrict__ out, float* __restrict__ ws)
{
  __shared__ unsigned wmh_pk[8][16][64];          // 32KB: wmh rows, bf16x2 packed
  __shared__ __align__(16) float fcx[4096];       // stageH (loop) / FC scratch
  __shared__ __align__(16) float fy[2048];        // stageM (loop) / FC scratch

  const int tid  = threadIdx.x;
  const int lane = tid & 63;
  const int wv   = tid >> 6;        // wave 0..3 owns units 2wv, 2wv+1
  const int b    = blockIdx.x;      // CU id 0..255

  unsigned* h_pack = (unsigned*)ws + WS_HP;
  unsigned* m_pack = (unsigned*)ws + WS_MP;
  unsigned* hF     = (unsigned*)ws + WS_HF;
  unsigned* cF     = (unsigned*)ws + WS_CF;
  float* stageH = fcx;
  float* stageM = fy;

  // ---------------- preload weights ----------------
  // s = 4*rr + type: wave wv, unit u = 8b + 2wv + rr, row = 2048*type + u.
  float whR[8][32];
  float wxR[8][2];
  float gBias[8];
#pragma unroll
  for (int s = 0; s < 8; ++s) {
    const int rs = 2048 * (s & 3) + 8 * b + 2 * wv + (s >> 2);
    const float* row = wh_w + (size_t)rs * 2048;
#pragma unroll
    for (int j = 0; j < 32; ++j) whR[s][j] = row[lane + 64 * j];
    wxR[s][0] = wx_w[(size_t)rs * 128 + lane];
    wxR[s][1] = wx_w[(size_t)rs * 128 + lane + 64];
    gBias[s] = wh_b[rs] + wx_b[rs];
  }
  float wmxR[2][2], vB[2], xB[2];
#pragma unroll
  for (int rr = 0; rr < 2; ++rr) {
    const int gu = 8 * b + 2 * wv + rr;
    wmxR[rr][0] = wmx_w[(size_t)gu * 128 + lane];
    wmxR[rr][1] = wmx_w[(size_t)gu * 128 + lane + 64];
    vB[rr] = wmh_b[gu];
    xB[rr] = wmx_b[gu];
  }
  // wmh rows -> LDS as packed bf16 pairs (RNE).
  for (int idx = tid; idx < 8 * 16 * 64; idx += 256) {
    int u = idx >> 10, p = (idx >> 6) & 15, l = idx & 63;
    float a = wmh_w[(size_t)(8 * b + u) * 2048 + l + 128 * p];
    float c = wmh_w[(size_t)(8 * b + u) * 2048 + l + 128 * p + 64];
    wmh_pk[u][p][l] = bf(a) | (bf(c) << 16);
  }
  __syncthreads();

  float c0 = 0.f, c1 = 0.f;        // f32 c-state (lane0's copy is canonical)
  int tok = tokens[0];
  float e0 = embed_w[tok * 128 + lane];
  float e1 = embed_w[tok * 128 + lane + 64];

  for (int t = 0; t < 8192; ++t) {
    // ---- phase 1: poll h(t) (tag t; t=0 from memset zeros), stage, m ----
    {
      u32x4 va, vb;
      while (!poll4p(h_pack + 8 * tid, (unsigned)t, &va, &vb))
        __builtin_amdgcn_s_sleep(1);
      stage8(&stageH[8 * tid], va, vb);
    }
    __syncthreads();                       // SYNC_A
    float hloc[32];
#pragma unroll
    for (int j = 0; j < 32; ++j) hloc[j] = stageH[lane + 64 * j];
    float mv[2];
#pragma unroll
    for (int rr = 0; rr < 2; ++rr) {
      float acc = 0.f;
#pragma unroll
      for (int p = 0; p < 16; ++p) {
        unsigned pk = wmh_pk[2 * wv + rr][p][lane];
        acc = fmaf(__uint_as_float(pk << 16),         hloc[2 * p],     acc);
        acc = fmaf(__uint_as_float(pk & 0xffff0000u), hloc[2 * p + 1], acc);
      }
      float ax = fmaf(wmxR[rr][0], e0, wmxR[rr][1] * e1);
      acc = wred(acc);
      ax  = wred(ax);
      mv[rr] = (ax + xB[rr]) * (acc + vB[rr]);   // m = xm * (wmh@h + b)
    }
    if (lane == 0)
      store_pack(m_pack + 2 * (4 * b + wv), mv[0], mv[1], (unsigned)(t + 1));

    // ---- phase 2: poll m(t) (tag t+1), stage, gates, c/h update ----
    {
      u32x4 va, vb;
      while (!poll4p(m_pack + 8 * tid, (unsigned)(t + 1), &va, &vb))
        __builtin_amdgcn_s_sleep(1);
      stage8(&stageM[8 * tid], va, vb);
    }
    __syncthreads();                       // SYNC_B
    float mloc[32];
#pragma unroll
    for (int j = 0; j < 32; ++j) mloc[j] = stageM[lane + 64 * j];
    float ga[8];
#pragma unroll
    for (int s = 0; s < 8; ++s) {
      float acc = fmaf(wxR[s][0], e0, wxR[s][1] * e1);   // x_gates folded in
#pragma unroll
      for (int j = 0; j < 32; ++j) acc = fmaf(whR[s][j], mloc[j], acc);
      ga[s] = acc;
    }
    // prefetch next token + embedding (hides under reductions)
    if (t + 1 < 8192) {
      tok = tokens[t + 1];
      e0 = embed_w[tok * 128 + lane];
      e1 = embed_w[tok * 128 + lane + 64];
    }
#pragma unroll
    for (int s = 0; s < 8; ++s) ga[s] = wred(ga[s]) + gBias[s];
    // all lanes compute identically (ga uniform after wred); lane0 stores
    c0 = sigm(ga[1]) * c0 + sigm(ga[0]) * tanhf(ga[2]);
    float h0 = sigm(ga[3]) * tanhf(c0);
    c1 = sigm(ga[5]) * c1 + sigm(ga[4]) * tanhf(ga[6]);
    float h1 = sigm(ga[7]) * tanhf(c1);
    if (lane == 0) {
      if (t + 1 < 8192) {
        store_pack(h_pack + 2 * (4 * b + wv), h0, h1, (unsigned)(t + 1));
      } else {
        // finals as exact f32 pairs
        const int u = 8 * b + 2 * wv;
        store_pair(hF + 2 * u,       h0, 8193u);
        store_pair(hF + 2 * (u + 1), h1, 8193u);
        store_pair(cF + 2 * u,       c0, 8193u);
        store_pair(cF + 2 * (u + 1), c1, 8193u);
      }
    }
  }

  if (b != 0) return;

  // ---- final FC chain on block 0 only (~10 MMAC) ----
  for (int i = tid; i < 2048; i += 256) {
    fcx[i]        = poll1(hF + 2 * i, 8193u);
    fcx[2048 + i] = poll1(cF + 2 * i, 8193u);
  }
  __syncthreads();
  // fc1: [2048 x 4096]
  for (int r = tid; r < 2048; r += 256) {
    const float4* wr = (const float4*)(fc1_w + (size_t)r * 4096);
    const float4* xv = (const float4*)fcx;
    float a0 = 0, a1 = 0, a2 = 0, a3 = 0;
    for (int k = 0; k < 1024; ++k) {
      float4 w = wr[k], x = xv[k];
      a0 = fmaf(w.x, x.x, a0); a1 = fmaf(w.y, x.y, a1);
      a2 = fmaf(w.z, x.z, a2); a3 = fmaf(w.w, x.w, a3);
    }
    fy[r] = fmaxf((a0 + a1) + (a2 + a3) + fc1_b[r], 0.f);
  }
  __syncthreads();
  // fc2: [512 x 2048]
  for (int r = tid; r < 512; r += 256) {
    const float4* wr = (const float4*)(fc2_w + (size_t)r * 2048);
    const float4* xv = (const float4*)fy;
    float a0 = 0, a1 = 0, a2 = 0, a3 = 0;
    for (int k = 0; k < 512; ++k) {
      float4 w = wr[k], x = xv[k];
      a0 = fmaf(w.x, x.x, a0); a1 = fmaf(w.y, x.y, a1);
      a2 = fmaf(w.z, x.z, a2); a3 = fmaf(w.w, x.w, a3);
    }
    fcx[r] = fmaxf((a0 + a1) + (a2 + a3) + fc2_b[r], 0.f);
  }
  __syncthreads();
  // fc3: [1024 x 512]
  for (int r = tid; r < 1024; r += 256) {
    const float4* wr = (const float4*)(fc3_w + (size_t)r * 512);
    const float4* xv = (const float4*)fcx;
    float a0 = 0, a1 = 0, a2 = 0, a3 = 0;
    for (int k = 0; k < 128; ++k) {
      float4 w = wr[k], x = xv[k];
      a0 = fmaf(w.x, x.x, a0); a1 = fmaf(w.y, x.y, a1);
      a2 = fmaf(w.z, x.z, a2); a3 = fmaf(w.w, x.w, a3);
    }
    fy[r] = fmaxf((a0 + a1) + (a2 + a3) + fc3_b[r], 0.f);
  }
  __syncthreads();
  // fc4: [5 x 1024]
  if (tid < 5) {
    const float4* wr = (const float4*)(fc4_w + (size_t)tid * 1024);
    const float4* xv = (const float4*)fy;
    float a0 = 0, a1 = 0, a2 = 0, a3 = 0;
    for (int k = 0; k < 256; ++k) {
      float4 w = wr[k], x = xv[k];
      a0 = fmaf(w.x, x.x, a0); a1 = fmaf(w.y, x.y, a1);
      a2 = fmaf(w.z, x.z, a2); a3 = fmaf(w.w, x.w, a3);
    }
    out[tid] = fmaxf((a0 + a1) + (a2 + a3) + fc4_b[tid], 0.f);
  }
}

extern "C" void kernel_launch(void* const* d_in, const int* in_sizes, int n_in,
                              void* d_out, int out_size, void* d_ws, size_t ws_size,
                              hipStream_t stream)
{
  const int*   tokens = (const int*)  d_in[0];
  const float* embed_w = (const float*)d_in[1];
  const float* wx_w   = (const float*)d_in[2];
  const float* wx_b   = (const float*)d_in[3];
  const float* wh_w   = (const float*)d_in[4];
  const float* wh_b   = (const float*)d_in[5];
  const float* wmx_w  = (const float*)d_in[6];
  const float* wmx_b  = (const float*)d_in[7];
  const float* wmh_w  = (const float*)d_in[8];
  const float* wmh_b  = (const float*)d_in[9];
  const float* fc1_w  = (const float*)d_in[10];
  const float* fc1_b  = (const float*)d_in[11];
  const float* fc2_w  = (const float*)d_in[12];
  const float* fc2_b  = (const float*)d_in[13];
  const float* fc3_w  = (const float*)d_in[14];
  const float* fc3_b  = (const float*)d_in[15];
  const float* fc4_w  = (const float*)d_in[16];
  const float* fc4_b  = (const float*)d_in[17];
  float* out = (float*)d_out;
  float* ws  = (float*)d_ws;

  // zero all packets/tags every call (graph-replay safe; h tag 0 == h(0)=0)
  hipMemsetAsync(d_ws, 0, WS_TOT * sizeof(float), stream);

  mlstm_kernel<<<dim3(256), dim3(256), 0, stream>>>(
      tokens, embed_w, wx_w, wx_b, wh_w, wh_b,
      wmx_w, wmx_b, wmh_w, wmh_b,
      fc1_w, fc1_b, fc2_w, fc2_b, fc3_w, fc3_b,
      fc4_w, fc4_b, out, ws);
}

// Round 9
// 74314.996 us; speedup vs baseline: 1.1647x; 1.0004x over previous
//
#include <hip/hip_runtime.h>
#include <math.h>

// mLSTM scan, 8192 serial steps. Weights resident on-chip (wh_w f32 in
// regs: 256/thread; wmh_w bf16-packed in LDS: 32KB/CU), one persistent
// workgroup per CU (256 x 256), per-step cross-CU exchange of the
// 2048-vectors m and h through the device coherence point. FC on block 0.
//
// R8 -> R9: REVERT the XCD mirror fan-out (deadlocked: sc0 intra-XCD
// visibility assumptions unsafe). Back to R7 structure with ONE change:
// all exchange ops use DEVICE scope (sc1) instead of SYSTEM scope
// (sc0 sc1). gfx940+ scope encoding: SC1:SC0 = 00 CU / 01 SE / 10 device
// / 11 system. System scope (what R3-R7 used) is host-coherent and
// plausibly bypasses/no-allocates the LLC -> every poll RT was HBM-class
// (evidence: FETCH ~15x fresh bytes/step; ~3.5us/phase constant immune to
// three protocol rewrites). Device scope is the cross-XCD coherence point
// (LLC) -- sufficient for GPU-only exchange, and LLC-resident.

#define WS_HP   0          // h packets: 1024 x (bf16x2, tag) = 2048 words
#define WS_MP   2048       // m packets: 2048 words
#define WS_HF   4096       // final h: 2048 x (f32, tag) = 4096 words
#define WS_CF   8192       // final c: 4096 words
#define WS_TOT  12288      // words (48 KB)

typedef unsigned u32x4 __attribute__((ext_vector_type(4)));
typedef unsigned u32x2 __attribute__((ext_vector_type(2)));

__device__ __forceinline__ float sigm(float x) { return 1.f / (1.f + __expf(-x)); }

__device__ __forceinline__ float wred(float v) {
  v += __shfl_xor(v, 32, 64);
  v += __shfl_xor(v, 16, 64);
  v += __shfl_xor(v, 8, 64);
  v += __shfl_xor(v, 4, 64);
  v += __shfl_xor(v, 2, 64);
  v += __shfl_xor(v, 1, 64);
  return v;
}

// RNE f32 -> bf16 bits (low 16).
__device__ __forceinline__ unsigned bf(float f) {
  unsigned x = __float_as_uint(f);
  return (x + 0x7fffu + ((x >> 16) & 1u)) >> 16;
}

// One 8B packet: (bf16 v0 | bf16 v1 << 16, tag32), device-scope store.
__device__ __forceinline__ void store_pack(unsigned* p, float v0, float v1,
                                           unsigned tag) {
  u32x2 q; q.x = bf(v0) | (bf(v1) << 16); q.y = tag;
  asm volatile("global_store_dwordx2 %0, %1, off sc1"
               :: "v"(p), "v"(q) : "memory");
}

// f32 (value, tag) pair store (finals only), device scope.
__device__ __forceinline__ void store_pair(unsigned* p, float v, unsigned tag) {
  u32x2 q; q.x = __float_as_uint(v); q.y = tag;
  asm volatile("global_store_dwordx2 %0, %1, off sc1"
               :: "v"(p), "v"(q) : "memory");
}

// Poll 4 packets (32B = 8 scalars) at device scope; true when all tags match.
__device__ __forceinline__ bool poll4p(const unsigned* p, unsigned expect,
                                       u32x4* va, u32x4* vb) {
  u32x4 a, b;
  asm volatile(
      "global_load_dwordx4 %0, %2, off sc1\n\t"
      "global_load_dwordx4 %1, %2, off offset:16 sc1\n\t"
      "s_waitcnt vmcnt(0)"
      : "=&v"(a), "=&v"(b) : "v"(p) : "memory");
  bool ok = (a.y == expect) & (a.w == expect) & (b.y == expect) & (b.w == expect);
  *va = a; *vb = b;
  return ok;
}

// Scalar f32 pair poll (FC tail only), device scope.
__device__ __forceinline__ float poll1(const unsigned* p, unsigned expect) {
  for (;;) {
    u32x2 q;
    asm volatile("global_load_dwordx2 %0, %1, off sc1\n\t"
                 "s_waitcnt vmcnt(0)"
                 : "=&v"(q) : "v"(p) : "memory");
    if (q.y == expect) return __uint_as_float(q.x);
    __builtin_amdgcn_s_sleep(1);
  }
}

// Unpack 8 bf16 scalars from 2 packets' value-dwords into LDS stage.
__device__ __forceinline__ void stage8(float* s, u32x4 a, u32x4 b) {
  s[0] = __uint_as_float(a.x << 16);
  s[1] = __uint_as_float(a.x & 0xffff0000u);
  s[2] = __uint_as_float(a.z << 16);
  s[3] = __uint_as_float(a.z & 0xffff0000u);
  s[4] = __uint_as_float(b.x << 16);
  s[5] = __uint_as_float(b.x & 0xffff0000u);
  s[6] = __uint_as_float(b.z << 16);
  s[7] = __uint_as_float(b.z & 0xffff0000u);
}

__global__ __launch_bounds__(256, 1)
void mlstm_kernel(const int* __restrict__ tokens,
                  const float* __restrict__ embed_w,
                  const float* __restrict__ wx_w,  const float* __restrict__ wx_b,
                  const float* __restrict__ wh_w,  const float* __restrict__ wh_b,
                  const float* __restrict__ wmx_w, const float* __restrict__ wmx_b,
                  const float* __restrict__ wmh_w, const float* __restrict__ wmh_b,
                  const float* __restrict__ fc1_w, const float* __restrict__ fc1_b,
                  const float* __restrict__ fc2_w, const float* __restrict__ fc2_b,
                  const float* __restrict__ fc3_w, const float* __restrict__ fc3_b,
                  const float* __restrict__ fc4_w, const float* __restrict__ fc4_b,
                  float* __restrict__ out, float* __restrict__ ws)
{
  __shared__ unsigned wmh_pk[8][16][64];          // 32KB: wmh rows, bf16x2 packed
  __shared__ __align__(16) float fcx[4096];       // stageH (loop) / FC scratch
  __shared__ __align__(16) float fy[2048];        // stageM (loop) / FC scratch

  const int tid  = threadIdx.x;
  const int lane = tid & 63;
  const int wv   = tid >> 6;        // wave 0..3 owns units 2wv, 2wv+1
  const int b    = blockIdx.x;      // CU id 0..255

  unsigned* h_pack = (unsigned*)ws + WS_HP;
  unsigned* m_pack = (unsigned*)ws + WS_MP;
  unsigned* hF     = (unsigned*)ws + WS_HF;
  unsigned* cF     = (unsigned*)ws + WS_CF;
  float* stageH = fcx;
  float* stageM = fy;

  // ---------------- preload weights ----------------
  // s = 4*rr + type: wave wv, unit u = 8b + 2wv + rr, row = 2048*type + u.
  float whR[8][32];
  float wxR[8][2];
  float gBias[8];
#pragma unroll
  for (int s = 0; s < 8; ++s) {
    const int rs = 2048 * (s & 3) + 8 * b + 2 * wv + (s >> 2);
    const float* row = wh_w + (size_t)rs * 2048;
#pragma unroll
    for (int j = 0; j < 32; ++j) whR[s][j] = row[lane + 64 * j];
    wxR[s][0] = wx_w[(size_t)rs * 128 + lane];
    wxR[s][1] = wx_w[(size_t)rs * 128 + lane + 64];
    gBias[s] = wh_b[rs] + wx_b[rs];
  }
  float wmxR[2][2], vB[2], xB[2];
#pragma unroll
  for (int rr = 0; rr < 2; ++rr) {
    const int gu = 8 * b + 2 * wv + rr;
    wmxR[rr][0] = wmx_w[(size_t)gu * 128 + lane];
    wmxR[rr][1] = wmx_w[(size_t)gu * 128 + lane + 64];
    vB[rr] = wmh_b[gu];
    xB[rr] = wmx_b[gu];
  }
  // wmh rows -> LDS as packed bf16 pairs (RNE).
  for (int idx = tid; idx < 8 * 16 * 64; idx += 256) {
    int u = idx >> 10, p = (idx >> 6) & 15, l = idx & 63;
    float a = wmh_w[(size_t)(8 * b + u) * 2048 + l + 128 * p];
    float c = wmh_w[(size_t)(8 * b + u) * 2048 + l + 128 * p + 64];
    wmh_pk[u][p][l] = bf(a) | (bf(c) << 16);
  }
  __syncthreads();

  float c0 = 0.f, c1 = 0.f;        // f32 c-state
  int tok = tokens[0];
  float e0 = embed_w[tok * 128 + lane];
  float e1 = embed_w[tok * 128 + lane + 64];

  for (int t = 0; t < 8192; ++t) {
    // ---- phase 1: poll h(t) (tag t; t=0 from memset zeros), stage, m ----
    {
      u32x4 va, vb;
      while (!poll4p(h_pack + 8 * tid, (unsigned)t, &va, &vb))
        __builtin_amdgcn_s_sleep(1);
      stage8(&stageH[8 * tid], va, vb);
    }
    __syncthreads();                       // SYNC_A
    float hloc[32];
#pragma unroll
    for (int j = 0; j < 32; ++j) hloc[j] = stageH[lane + 64 * j];
    float mv[2];
#pragma unroll
    for (int rr = 0; rr < 2; ++rr) {
      float acc = 0.f;
#pragma unroll
      for (int p = 0; p < 16; ++p) {
        unsigned pk = wmh_pk[2 * wv + rr][p][lane];
        acc = fmaf(__uint_as_float(pk << 16),         hloc[2 * p],     acc);
        acc = fmaf(__uint_as_float(pk & 0xffff0000u), hloc[2 * p + 1], acc);
      }
      float ax = fmaf(wmxR[rr][0], e0, wmxR[rr][1] * e1);
      acc = wred(acc);
      ax  = wred(ax);
      mv[rr] = (ax + xB[rr]) * (acc + vB[rr]);   // m = xm * (wmh@h + b)
    }
    if (lane == 0)
      store_pack(m_pack + 2 * (4 * b + wv), mv[0], mv[1], (unsigned)(t + 1));

    // ---- phase 2: poll m(t) (tag t+1), stage, gates, c/h update ----
    {
      u32x4 va, vb;
      while (!poll4p(m_pack + 8 * tid, (unsigned)(t + 1), &va, &vb))
        __builtin_amdgcn_s_sleep(1);
      stage8(&stageM[8 * tid], va, vb);
    }
    __syncthreads();                       // SYNC_B
    float mloc[32];
#pragma unroll
    for (int j = 0; j < 32; ++j) mloc[j] = stageM[lane + 64 * j];
    float ga[8];
#pragma unroll
    for (int s = 0; s < 8; ++s) {
      float acc = fmaf(wxR[s][0], e0, wxR[s][1] * e1);   // x_gates folded in
#pragma unroll
      for (int j = 0; j < 32; ++j) acc = fmaf(whR[s][j], mloc[j], acc);
      ga[s] = acc;
    }
    // prefetch next token + embedding (hides under reductions)
    if (t + 1 < 8192) {
      tok = tokens[t + 1];
      e0 = embed_w[tok * 128 + lane];
      e1 = embed_w[tok * 128 + lane + 64];
    }
#pragma unroll
    for (int s = 0; s < 8; ++s) ga[s] = wred(ga[s]) + gBias[s];
    // all lanes compute identically (ga uniform after wred); lane0 stores
    c0 = sigm(ga[1]) * c0 + sigm(ga[0]) * tanhf(ga[2]);
    float h0 = sigm(ga[3]) * tanhf(c0);
    c1 = sigm(ga[5]) * c1 + sigm(ga[4]) * tanhf(ga[6]);
    float h1 = sigm(ga[7]) * tanhf(c1);
    if (lane == 0) {
      if (t + 1 < 8192) {
        store_pack(h_pack + 2 * (4 * b + wv), h0, h1, (unsigned)(t + 1));
      } else {
        // finals as exact f32 pairs
        const int u = 8 * b + 2 * wv;
        store_pair(hF + 2 * u,       h0, 8193u);
        store_pair(hF + 2 * (u + 1), h1, 8193u);
        store_pair(cF + 2 * u,       c0, 8193u);
        store_pair(cF + 2 * (u + 1), c1, 8193u);
      }
    }
  }

  if (b != 0) return;

  // ---- final FC chain on block 0 only (~10 MMAC) ----
  for (int i = tid; i < 2048; i += 256) {
    fcx[i]        = poll1(hF + 2 * i, 8193u);
    fcx[2048 + i] = poll1(cF + 2 * i, 8193u);
  }
  __syncthreads();
  // fc1: [2048 x 4096]
  for (int r = tid; r < 2048; r += 256) {
    const float4* wr = (const float4*)(fc1_w + (size_t)r * 4096);
    const float4* xv = (const float4*)fcx;
    float a0 = 0, a1 = 0, a2 = 0, a3 = 0;
    for (int k = 0; k < 1024; ++k) {
      float4 w = wr[k], x = xv[k];
      a0 = fmaf(w.x, x.x, a0); a1 = fmaf(w.y, x.y, a1);
      a2 = fmaf(w.z, x.z, a2); a3 = fmaf(w.w, x.w, a3);
    }
    fy[r] = fmaxf((a0 + a1) + (a2 + a3) + fc1_b[r], 0.f);
  }
  __syncthreads();
  // fc2: [512 x 2048]
  for (int r = tid; r < 512; r += 256) {
    const float4* wr = (const float4*)(fc2_w + (size_t)r * 2048);
    const float4* xv = (const float4*)fy;
    float a0 = 0, a1 = 0, a2 = 0, a3 = 0;
    for (int k = 0; k < 512; ++k) {
      float4 w = wr[k], x = xv[k];
      a0 = fmaf(w.x, x.x, a0); a1 = fmaf(w.y, x.y, a1);
      a2 = fmaf(w.z, x.z, a2); a3 = fmaf(w.w, x.w, a3);
    }
    fcx[r] = fmaxf((a0 + a1) + (a2 + a3) + fc2_b[r], 0.f);
  }
  __syncthreads();
  // fc3: [1024 x 512]
  for (int r = tid; r < 1024; r += 256) {
    const float4* wr = (const float4*)(fc3_w + (size_t)r * 512);
    const float4* xv = (const float4*)fcx;
    float a0 = 0, a1 = 0, a2 = 0, a3 = 0;
    for (int k = 0; k < 128; ++k) {
      float4 w = wr[k], x = xv[k];
      a0 = fmaf(w.x, x.x, a0); a1 = fmaf(w.y, x.y, a1);
      a2 = fmaf(w.z, x.z, a2); a3 = fmaf(w.w, x.w, a3);
    }
    fy[r] = fmaxf((a0 + a1) + (a2 + a3) + fc3_b[r], 0.f);
  }
  __syncthreads();
  // fc4: [5 x 1024]
  if (tid < 5) {
    const float4* wr = (const float4*)(fc4_w + (size_t)tid * 1024);
    const float4* xv = (const float4*)fy;
    float a0 = 0, a1 = 0, a2 = 0, a3 = 0;
    for (int k = 0; k < 256; ++k) {
      float4 w = wr[k], x = xv[k];
      a0 = fmaf(w.x, x.x, a0); a1 = fmaf(w.y, x.y, a1);
      a2 = fmaf(w.z, x.z, a2); a3 = fmaf(w.w, x.w, a3);
    }
    out[tid] = fmaxf((a0 + a1) + (a2 + a3) + fc4_b[tid], 0.f);
  }
}

extern "C" void kernel_launch(void* const* d_in, const int* in_sizes, int n_in,
                              void* d_out, int out_size, void* d_ws, size_t ws_size,
                              hipStream_t stream)
{
  const int*   tokens = (const int*)  d_in[0];
  const float* embed_w = (const float*)d_in[1];
  const float* wx_w   = (const float*)d_in[2];
  const float* wx_b   = (const float*)d_in[3];
  const float* wh_w   = (const float*)d_in[4];
  const float* wh_b   = (const float*)d_in[5];
  const float* wmx_w  = (const float*)d_in[6];
  const float* wmx_b  = (const float*)d_in[7];
  const float* wmh_w  = (const float*)d_in[8];
  const float* wmh_b  = (const float*)d_in[9];
  const float* fc1_w  = (const float*)d_in[10];
  const float* fc1_b  = (const float*)d_in[11];
  const float* fc2_w  = (const float*)d_in[12];
  const float* fc2_b  = (const float*)d_in[13];
  const float* fc3_w  = (const float*)d_in[14];
  const float* fc3_b  = (const float*)d_in[15];
  const float* fc4_w  = (const float*)d_in[16];
  const float* fc4_b  = (const float*)d_in[17];
  float* out = (float*)d_out;
  float* ws  = (float*)d_ws;

  // zero all packets/tags every call (graph-replay safe; h tag 0 == h(0)=0)
  hipMemsetAsync(d_ws, 0, WS_TOT * sizeof(float), stream);

  mlstm_kernel<<<dim3(256), dim3(256), 0, stream>>>(
      tokens, embed_w, wx_w, wx_b, wh_w, wh_b,
      wmx_w, wmx_b, wmh_w, wmh_b,
      fc1_w, fc1_b, fc2_w, fc2_b, fc3_w, fc3_b,
      fc4_w, fc4_b, out, ws);
}